// Round 1
// baseline (8265.523 us; speedup 1.0000x reference)
//
#include <hip/hip_runtime.h>
#include <hip/hip_bf16.h>
#include <math.h>

#define N_PART 512
#define T_STEPS 128
#define V_L 3.4f
#define V_0 4.2f
#define GAMMA 0.9f
#define ALPHA 0.15f
#define BETA 15.0f
#define E_CRIT_INV 2e-5f
#define F_STD 0.05f
#define G_STD 0.02f

__device__ __forceinline__ float sigmoid_jax(float x) {
    // match jax.nn.sigmoid stable formulation
    if (x >= 0.f) return 1.f / (1.f + expf(-x));
    float e = expf(x);
    return e / (1.f + e);
}

__device__ __forceinline__ float vocf(float s) {
    float e1 = expf(GAMMA * (s - 1.f));
    float e2 = expf(-BETA * sqrtf(s));
    return V_L + (V_0 - V_L) * e1 + ALPHA * V_L * (s - 1.f)
         + (1.f - ALPHA) * V_L * (expf(-BETA) - e2);
}

// K1: particle state update (or init) + layer 1.  grid = 512 blocks (one per particle), 256 threads.
__global__ __launch_bounds__(256) void k_update_l1(
    const float* __restrict__ soc_init, const float* __restrict__ current,
    const float* __restrict__ noise, const float* __restrict__ w1,
    const float* __restrict__ b1,
    float* __restrict__ soc_buf, const float* __restrict__ V_buf,
    float* __restrict__ h1, int t, int initmode)
{
    int i = blockIdx.x;
    int tx = threadIdx.x;
    float soc;
    if (initmode) {
        soc = soc_init[i];
    } else {
        float Iprev = current[t == 0 ? 0 : t - 1];
        soc = soc_buf[i] - (Iprev * V_buf[i]) * E_CRIT_INV + F_STD * noise[t * N_PART + i];
        soc = (soc > 1.f) ? 1.f : ((soc < 0.f) ? 1e-10f : soc);
    }
    if (tx == 0) soc_buf[i] = soc;
    float sI = current[initmode ? 0 : t];   // CUR_MIN=0, CUR_MAX=1 -> sI = I
    #pragma unroll
    for (int m = 0; m < 4; ++m) {
        int j = tx + m * 256;
        float pre = soc * w1[j] + sI * w1[1024 + j] + b1[j];
        h1[i * 1024 + j] = sigmoid_jax(pre);
    }
}

// K2: layer 2 GEMM (h1[512x1024] @ w2[1024x512]) + sigmoid + partial Z per column tile.
// grid = (16,16) tiles of 32x32, 256 threads.
__global__ __launch_bounds__(256) void k_gemm(
    const float* __restrict__ h1, const float* __restrict__ w2,
    const float* __restrict__ b2, const float* __restrict__ w3,
    float* __restrict__ zpart)
{
    int bx = blockIdx.x;  // col tile
    int by = blockIdx.y;  // row tile
    int tx = threadIdx.x & 31;
    int ty = threadIdx.x >> 5;
    __shared__ float As[32][33];
    __shared__ float Bs[32][33];
    float acc[4] = {0.f, 0.f, 0.f, 0.f};

    for (int kk = 0; kk < 1024; kk += 32) {
        #pragma unroll
        for (int m = 0; m < 4; ++m) {
            int r = ty + 8 * m;
            As[r][tx] = h1[(by * 32 + r) * 1024 + kk + tx];
            Bs[r][tx] = w2[(kk + r) * 512 + bx * 32 + tx];
        }
        __syncthreads();
        #pragma unroll
        for (int k = 0; k < 32; ++k) {
            float b = Bs[k][tx];
            #pragma unroll
            for (int m = 0; m < 4; ++m) acc[m] += As[ty + 8 * m][k] * b;
        }
        __syncthreads();
    }

    __shared__ float red[32][33];
    float w3c = w3[bx * 32 + tx];
    float b2c = b2[bx * 32 + tx];
    #pragma unroll
    for (int m = 0; m < 4; ++m) {
        float pre = acc[m] + b2c;
        float h2 = sigmoid_jax(pre);
        red[ty + 8 * m][tx] = h2 * w3c;
    }
    __syncthreads();
    for (int s = 16; s > 0; s >>= 1) {
        if (tx < s) {
            #pragma unroll
            for (int m = 0; m < 4; ++m) red[ty + 8 * m][tx] += red[ty + 8 * m][tx + s];
        }
        __syncthreads();
    }
    if (tx == 0) {
        #pragma unroll
        for (int m = 0; m < 4; ++m)
            zpart[bx * 512 + by * 32 + ty + 8 * m] = red[ty + 8 * m][0];
    }
}

// K3: finish step: Z, V, logW, logsumexp loss, softmax, cumsum, systematic resample.
// 1 block, 512 threads (thread i = particle i).
__global__ __launch_bounds__(512) void k_finish(
    const float* __restrict__ zpart, const float* __restrict__ b3,
    float* __restrict__ soc_buf, float* __restrict__ V_buf,
    const float* __restrict__ current, const float* __restrict__ vmeas,
    const float* __restrict__ u, float* __restrict__ losses,
    float* __restrict__ out, int t, int initmode)
{
    int i = threadIdx.x;
    float z = 0.f;
    #pragma unroll
    for (int cb = 0; cb < 16; ++cb) z += zpart[cb * 512 + i];
    z += b3[0];
    float soc = soc_buf[i];
    float I = current[t];
    float V = vocf(soc) - I * z;
    if (initmode) { V_buf[i] = V; return; }

    const float NUF = (float)(1.0 / (0.02 * 2.5066282746310002));  // 1/(G_STD*sqrt(2pi))
    float lw = logf(NUF) - 0.5f * ((V - vmeas[t]) / G_STD) * ((V - vmeas[t]) / G_STD);

    __shared__ float red[512];
    __shared__ float socs[512];
    __shared__ float cum[512];
    socs[i] = soc;

    // max reduce
    red[i] = lw; __syncthreads();
    for (int s = 256; s > 0; s >>= 1) {
        if (i < s) red[i] = fmaxf(red[i], red[i + s]);
        __syncthreads();
    }
    float M = red[0]; __syncthreads();

    float e = expf(lw - M);
    red[i] = e; __syncthreads();
    for (int s = 256; s > 0; s >>= 1) {
        if (i < s) red[i] += red[i + s];
        __syncthreads();
    }
    float S = red[0]; __syncthreads();

    if (i == 0) losses[t] = (M + logf(S)) - logf(512.f);

    float wn = e / S;
    // inclusive scan (Hillis-Steele)
    cum[i] = wn; __syncthreads();
    for (int off = 1; off < 512; off <<= 1) {
        float v = cum[i];
        float a = (i >= off) ? cum[i - off] : 0.f;
        __syncthreads();
        cum[i] = v + a;
        __syncthreads();
    }

    float pos = ((float)i + u[t]) * (1.0f / 512.0f);
    // lower_bound: first idx with cum[idx] >= pos  (np.searchsorted side='left')
    int lo = 0, hi = 512;
    while (lo < hi) {
        int mid = (lo + hi) >> 1;
        if (cum[mid] < pos) lo = mid + 1; else hi = mid;
    }
    int idx = (lo < 511) ? lo : 511;
    float socr = socs[idx];

    out[1 + i * T_STEPS + t] = V;
    out[1 + N_PART * T_STEPS + i * T_STEPS + t] = socr;
    V_buf[i] = V;
    soc_buf[i] = socr;
}

__global__ void k_loss(const float* __restrict__ losses, float* __restrict__ out)
{
    if (threadIdx.x == 0) {
        float s = 0.f;
        for (int t = 0; t < T_STEPS; ++t) s += losses[t];
        out[0] = s;
    }
}

extern "C" void kernel_launch(void* const* d_in, const int* in_sizes, int n_in,
                              void* d_out, int out_size, void* d_ws, size_t ws_size,
                              hipStream_t stream)
{
    const float* soc_init = (const float*)d_in[0];
    const float* current  = (const float*)d_in[1];
    const float* vmeas    = (const float*)d_in[2];
    const float* noise    = (const float*)d_in[3];
    const float* u        = (const float*)d_in[4];
    const float* w1 = (const float*)d_in[5];
    const float* b1 = (const float*)d_in[6];
    const float* w2 = (const float*)d_in[7];
    const float* b2 = (const float*)d_in[8];
    const float* w3 = (const float*)d_in[9];
    const float* b3 = (const float*)d_in[10];
    float* out = (float*)d_out;
    float* ws  = (float*)d_ws;

    float* h1      = ws;                  // 512*1024
    float* zpart   = ws + 524288;         // 16*512
    float* soc_buf = zpart + 8192;        // 512
    float* V_buf   = soc_buf + 512;       // 512
    float* losses  = V_buf + 512;         // 128

    // pre-loop: V0 at soc_init with I0 = current[0]
    k_update_l1<<<512, 256, 0, stream>>>(soc_init, current, noise, w1, b1,
                                         soc_buf, V_buf, h1, 0, 1);
    k_gemm<<<dim3(16, 16), 256, 0, stream>>>(h1, w2, b2, w3, zpart);
    k_finish<<<1, 512, 0, stream>>>(zpart, b3, soc_buf, V_buf, current, vmeas, u,
                                    losses, out, 0, 1);

    for (int t = 0; t < T_STEPS; ++t) {
        k_update_l1<<<512, 256, 0, stream>>>(soc_init, current, noise, w1, b1,
                                             soc_buf, V_buf, h1, t, 0);
        k_gemm<<<dim3(16, 16), 256, 0, stream>>>(h1, w2, b2, w3, zpart);
        k_finish<<<1, 512, 0, stream>>>(zpart, b3, soc_buf, V_buf, current, vmeas, u,
                                        losses, out, t, 0);
    }
    k_loss<<<1, 64, 0, stream>>>(losses, out);
}

// Round 2
// 507.889 us; speedup vs baseline: 16.2743x; 16.2743x over previous
//
#include <hip/hip_runtime.h>
#include <hip/hip_bf16.h>
#include <math.h>

#define N_PART 512
#define T_STEPS 128
#define G_NODES 33
#define V_L 3.4f
#define V_0 4.2f
#define GAMMA 0.9f
#define ALPHA 0.15f
#define BETA 15.0f
#define E_CRIT_INV 2e-5f
#define F_STD 0.05f
#define G_STD 0.02f

__device__ __forceinline__ float sigmoid_jax(float x) {
    if (x >= 0.f) return 1.f / (1.f + expf(-x));
    float e = expf(x);
    return e / (1.f + e);
}

__device__ __forceinline__ float vocf(float s) {
    float e1 = expf(GAMMA * (s - 1.f));
    float e2 = expf(-BETA * sqrtf(s));
    return V_L + (V_0 - V_L) * e1 + ALPHA * V_L * (s - 1.f)
         + (1.f - ALPHA) * V_L * (expf(-BETA) - e2);
}

// ---------------------------------------------------------------------------
// Phase A: tabulate Z_t(s_g) = mlp([s_g, current[t]]) for t=0..127, g=0..32.
// rows r = t*33+g, M = 4224 = 132 blocks * 32 rows. Exact f32 MLP.
// Block: 256 threads, full N=512 column sweep with w3-reduction -> 1 scalar/row.
// ---------------------------------------------------------------------------
#define BKT 16
__global__ __launch_bounds__(256) void k_tab(
    const float* __restrict__ current, const float* __restrict__ w1,
    const float* __restrict__ b1, const float* __restrict__ w2,
    const float* __restrict__ b2, const float* __restrict__ w3,
    const float* __restrict__ b3, float* __restrict__ ztab)
{
    const int tid = threadIdx.x;
    const int r0 = blockIdx.x * 32;
    __shared__ float As[32][BKT + 1];
    __shared__ float Bs[BKT][512];
    __shared__ float srow[32], irow[32];

    if (tid < 32) {
        int r = r0 + tid;
        int t = r / G_NODES;
        int g = r % G_NODES;
        srow[tid] = (float)g * (1.0f / 32.0f);
        irow[tid] = current[t];
    }
    __syncthreads();

    const int rg = tid >> 5;   // 0..7 -> rows rg*4..rg*4+3
    const int ct = tid & 31;   // 0..31 -> cols ct*4 + j*128 + q
    float acc[4][16];
    #pragma unroll
    for (int a = 0; a < 4; ++a)
        #pragma unroll
        for (int b = 0; b < 16; ++b) acc[a][b] = 0.f;

    for (int kk = 0; kk < 1024; kk += BKT) {
        // A tile: compute h1 on the fly (layer 1 + sigmoid), 512 vals
        #pragma unroll
        for (int half = 0; half < 2; ++half) {
            int idx = tid + half * 256;
            int row = idx >> 4;
            int k = idx & 15;
            float pre = srow[row] * w1[kk + k] + irow[row] * w1[1024 + kk + k] + b1[kk + k];
            As[row][k] = sigmoid_jax(pre);
        }
        // B tile: w2 rows kk..kk+15, 2048 float4 coalesced
        #pragma unroll
        for (int j = 0; j < 8; ++j) {
            int vi = tid + j * 256;
            int k = vi >> 7;
            int c4 = vi & 127;
            float4 w = *(const float4*)&w2[(kk + k) * 512 + c4 * 4];
            *(float4*)&Bs[k][c4 * 4] = w;
        }
        __syncthreads();
        #pragma unroll
        for (int k = 0; k < BKT; ++k) {
            float a0 = As[rg * 4 + 0][k];
            float a1 = As[rg * 4 + 1][k];
            float a2 = As[rg * 4 + 2][k];
            float a3 = As[rg * 4 + 3][k];
            float bq[16];
            #pragma unroll
            for (int j = 0; j < 4; ++j)
                *(float4*)&bq[j * 4] = *(const float4*)&Bs[k][ct * 4 + j * 128];
            #pragma unroll
            for (int q = 0; q < 16; ++q) {
                acc[0][q] += a0 * bq[q];
                acc[1][q] += a1 * bq[q];
                acc[2][q] += a2 * bq[q];
                acc[3][q] += a3 * bq[q];
            }
        }
        __syncthreads();
    }

    // epilogue: h2 = sigmoid(acc + b2), z-partial = sum w3[c]*h2
    float b2r[16], w3r[16];
    #pragma unroll
    for (int j = 0; j < 4; ++j)
        #pragma unroll
        for (int q = 0; q < 4; ++q) {
            int c = ct * 4 + j * 128 + q;
            b2r[j * 4 + q] = b2[c];
            w3r[j * 4 + q] = w3[c];
        }
    float zp[4] = {0.f, 0.f, 0.f, 0.f};
    #pragma unroll
    for (int rr = 0; rr < 4; ++rr)
        #pragma unroll
        for (int q = 0; q < 16; ++q)
            zp[rr] += w3r[q] * sigmoid_jax(acc[rr][q] + b2r[q]);

    // butterfly all-reduce across the 32 ct lanes (xor bits 0..4 stay in-group)
    #pragma unroll
    for (int mm = 1; mm < 32; mm <<= 1) {
        #pragma unroll
        for (int rr = 0; rr < 4; ++rr) zp[rr] += __shfl_xor(zp[rr], mm);
    }
    if (ct == 0) {
        float bb3 = b3[0];
        #pragma unroll
        for (int rr = 0; rr < 4; ++rr)
            ztab[r0 + rg * 4 + rr] = zp[rr] + bb3;
    }
}

// ---------------------------------------------------------------------------
// Cubic Lagrange interpolation of Z_t at soc, from LDS table row (33 nodes, h=1/32)
// ---------------------------------------------------------------------------
__device__ __forceinline__ float interp_z(const float* zt_row, float soc) {
    float x = soc * 32.0f;
    int j = (int)floorf(x);
    j = j > 31 ? 31 : (j < 0 ? 0 : j);
    int st = j - 1;
    st = st < 0 ? 0 : (st > 29 ? 29 : st);
    float uu = x - (float)st;
    float um0 = uu, um1 = uu - 1.f, um2 = uu - 2.f, um3 = uu - 3.f;
    float w0 = um1 * um2 * um3 * (-1.f / 6.f);
    float w1 = um0 * um2 * um3 * (0.5f);
    float w2 = um0 * um1 * um3 * (-0.5f);
    float w3 = um0 * um1 * um2 * (1.f / 6.f);
    return w0 * zt_row[st] + w1 * zt_row[st + 1] + w2 * zt_row[st + 2] + w3 * zt_row[st + 3];
}

// ---------------------------------------------------------------------------
// Phase B: the whole sequential filter in ONE block (512 threads = particles).
// ---------------------------------------------------------------------------
__global__ __launch_bounds__(512) void k_seq(
    const float* __restrict__ ztab, const float* __restrict__ soc_init,
    const float* __restrict__ current, const float* __restrict__ vmeas,
    const float* __restrict__ u, const float* __restrict__ noise,
    float* __restrict__ out)
{
    const int i = threadIdx.x;
    const int lane = i & 63;
    const int wid = i >> 6;

    __shared__ float zt[T_STEPS * G_NODES];
    __shared__ float socs[512];
    __shared__ float cum[512];
    __shared__ float red[16];
    __shared__ float cur_s[128], vm_s[128], u_s[128];

    for (int j = i; j < T_STEPS * G_NODES; j += 512) zt[j] = ztab[j];
    if (i < 128) { cur_s[i] = current[i]; vm_s[i] = vmeas[i]; u_s[i] = u[i]; }
    __syncthreads();

    float soc = soc_init[i];
    float V = vocf(soc) - cur_s[0] * interp_z(&zt[0], soc);   // V0 (t=0 table row)
    float Iprev = cur_s[0];
    float loss_acc = 0.f;
    const float LOG_NU = logf(19.947114020071635f);
    const float LOG_N = logf(512.f);

    for (int t = 0; t < T_STEPS; ++t) {
        // state propagation + clamp
        soc = soc - Iprev * V * E_CRIT_INV + F_STD * noise[t * 512 + i];
        soc = soc > 1.f ? 1.f : (soc < 0.f ? 1e-10f : soc);
        socs[i] = soc;

        float I = cur_s[t];
        float Z = interp_z(&zt[t * G_NODES], soc);
        V = vocf(soc) - I * Z;
        float d = (V - vm_s[t]) * (1.f / G_STD);
        float lw = LOG_NU - 0.5f * d * d;

        // max all-reduce
        float m = lw;
        #pragma unroll
        for (int mm = 1; mm < 64; mm <<= 1) m = fmaxf(m, __shfl_xor(m, mm));
        if (lane == 0) red[wid] = m;
        __syncthreads();
        float M = red[0];
        #pragma unroll
        for (int w = 1; w < 8; ++w) M = fmaxf(M, red[w]);
        __syncthreads();

        // sum all-reduce of e = exp(lw - M)
        float e = expf(lw - M);
        float s = e;
        #pragma unroll
        for (int mm = 1; mm < 64; mm <<= 1) s += __shfl_xor(s, mm);
        if (lane == 0) red[wid] = s;
        __syncthreads();
        float S = red[0];
        #pragma unroll
        for (int w = 1; w < 8; ++w) S += red[w];

        if (i == 0) loss_acc += M + logf(S) - LOG_N;

        // inclusive scan of wn = e/S
        float wn = e / S;
        float v2 = wn;
        #pragma unroll
        for (int dd = 1; dd < 64; dd <<= 1) {
            float tmp = __shfl_up(v2, dd);
            if (lane >= dd) v2 += tmp;
        }
        if (lane == 63) red[8 + wid] = v2;   // distinct slots: no clash with red[0..7] readers
        __syncthreads();
        float off = 0.f;
        #pragma unroll
        for (int w = 0; w < 8; ++w) off += (w < wid) ? red[8 + w] : 0.f;
        cum[i] = off + v2;
        __syncthreads();

        // systematic resample: searchsorted(cum, pos, side='left'), clip to 511
        float pos = ((float)i + u_s[t]) * (1.f / 512.f);
        int lo = 0, hi = 512;
        while (lo < hi) {
            int mid = (lo + hi) >> 1;
            if (cum[mid] < pos) lo = mid + 1; else hi = mid;
        }
        int idx = lo < 511 ? lo : 511;
        float socr = socs[idx];

        out[1 + i * T_STEPS + t] = V;
        out[1 + N_PART * T_STEPS + i * T_STEPS + t] = socr;
        soc = socr;
        Iprev = I;
        __syncthreads();   // protect socs/cum/red before next iteration's writes
    }
    if (i == 0) out[0] = loss_acc;
}

extern "C" void kernel_launch(void* const* d_in, const int* in_sizes, int n_in,
                              void* d_out, int out_size, void* d_ws, size_t ws_size,
                              hipStream_t stream)
{
    const float* soc_init = (const float*)d_in[0];
    const float* current  = (const float*)d_in[1];
    const float* vmeas    = (const float*)d_in[2];
    const float* noise    = (const float*)d_in[3];
    const float* u        = (const float*)d_in[4];
    const float* w1 = (const float*)d_in[5];
    const float* b1 = (const float*)d_in[6];
    const float* w2 = (const float*)d_in[7];
    const float* b2 = (const float*)d_in[8];
    const float* w3 = (const float*)d_in[9];
    const float* b3 = (const float*)d_in[10];
    float* out = (float*)d_out;
    float* ztab = (float*)d_ws;   // 4224 floats

    k_tab<<<132, 256, 0, stream>>>(current, w1, b1, w2, b2, w3, b3, ztab);
    k_seq<<<1, 512, 0, stream>>>(ztab, soc_init, current, vmeas, u, noise, out);
}